// Round 8
// baseline (115.906 us; speedup 1.0000x reference)
//
#include <hip/hip_runtime.h>
#include <math.h>

#define NCV   30000
#define NX    60000
#define NM    8
#define LN_EPSF 1e-5f
#define NFORCE 9000000      // force floats (3M x 3); d_out = [energy, forces...]

#define NB_CV 512           // k_cv grid
#define JB    59            // z0 slabs of 1024 rows (R2-proven config)
#define NBX   235           // bwdx 256-row blocks per model
#define NB_MF 118           // k_mf grid (<=256 => co-resident => spin-safe)

// ---------------- workspace layout (float offsets) ----------------
#define WS_XRAW   0          // 60000  (cos | sin)
#define WS_DCV    60000      // 360000 dphi/dx TRANSPOSED [12][30000]
#define WS_G      420000     // 480000 dE/dxhat*gamma per model (8 x 60000)
#define WS_LNP    900000     // 1024: [512 sum_x | 512 sum_x2]
#define WS_Z0P    901024     // 8*59*64 = 30208 z0 partials
#define WS_DZ0    931232     // 512
#define WS_E      931744     // 8
#define WS_SGP    931752     // 8*235 = 1880
#define WS_SGXP   933632     // 1880
#define WS_VARSUM 935512     // 1
#define WS_TICKET 935513     // 1 (uint bits)
#define WS_SIGMA  935514     // 1
#define WS_FLAG   935515     // 1 (uint bits)
#define WS_ZTICK  935516     // 8 (uint bits): per-model z0 tickets

struct F3 { float x, y, z; };
__device__ __forceinline__ F3 f3sub(F3 a, F3 b){ return {a.x-b.x, a.y-b.y, a.z-b.z}; }
__device__ __forceinline__ F3 f3add(F3 a, F3 b){ return {a.x+b.x, a.y+b.y, a.z+b.z}; }
__device__ __forceinline__ F3 f3scale(F3 a, float s){ return {a.x*s, a.y*s, a.z*s}; }
__device__ __forceinline__ float f3dot(F3 a, F3 b){ return a.x*b.x + a.y*b.y + a.z*b.z; }
__device__ __forceinline__ F3 f3cross(F3 a, F3 b){
  return { a.y*b.z - a.z*b.y, a.z*b.x - a.x*b.z, a.x*b.y - a.y*b.x };
}

// reduce LN per-block partials -> out2[0]=mu, out2[1]=inv_std  (wave 0 only; caller syncs)
__device__ __forceinline__ void compute_mu_inv(const float* __restrict__ ws, float* out2, int tid) {
  if (tid < 64) {
    float a = 0.f, b = 0.f;
    #pragma unroll 4
    for (int k = tid; k < NB_CV; k += 64) { a += ws[WS_LNP + k]; b += ws[WS_LNP + NB_CV + k]; }
    #pragma unroll
    for (int o = 1; o < 64; o <<= 1) { a += __shfl_xor(a, o); b += __shfl_xor(b, o); }
    if (tid == 0) {
      float mu  = a * (1.f / NX);
      float var = b * (1.f / NX) - mu * mu;
      out2[0] = mu;
      out2[1] = 1.f / sqrtf(var + LN_EPSF);
    }
  }
}

// ---------------- K1: dihedrals + grads + LN partials + zero forces ----------------
__global__ void k_cv(const float* __restrict__ pos, const float* __restrict__ box,
                     const int* __restrict__ idx, float* __restrict__ ws,
                     float* __restrict__ out) {
  int tid = threadIdx.x;
  int gtid = blockIdx.x * 256 + tid;

  // zero forces (grid-stride float4) — k_cv is latency-bound, write BW here is free (R2-verified)
  {
    float4 z4 = {0.f, 0.f, 0.f, 0.f};
    float4* fz = (float4*)(out + 4);
    const int NF4 = (NFORCE - 4) / 4;
    for (int i = gtid; i < NF4; i += NB_CV * 256) fz[i] = z4;
    if (gtid == 0) {
      out[1] = 0.f; out[2] = 0.f; out[3] = 0.f; out[NFORCE] = 0.f;
      ws[WS_VARSUM] = 0.f;
      ((unsigned int*)ws)[WS_TICKET] = 0u;
      ((unsigned int*)ws)[WS_FLAG]   = 0u;
      #pragma unroll
      for (int m = 0; m < NM; m++) ((unsigned int*)ws)[WS_ZTICK + m] = 0u;
    }
  }

  float cx = 0.f, cx2 = 0.f;
  int i = gtid;
  if (i < NCV) {
    float bx = box[0], by = box[4], bz = box[8];
    int4 q4 = *(const int4*)(idx + i*4);
    int pidx[4] = {q4.x, q4.y, q4.z, q4.w};
    F3 p[4];
    #pragma unroll
    for (int a = 0; a < 4; a++) {
      int pi = pidx[a];
      float X = pos[(size_t)pi*3 + 0];
      float Y = pos[(size_t)pi*3 + 1];
      float Z = pos[(size_t)pi*3 + 2];
      X -= floorf(X / bx) * bx;
      Y -= floorf(Y / by) * by;
      Z -= floorf(Z / bz) * bz;
      p[a] = {X, Y, Z};
    }
    F3 b1 = f3sub(p[1], p[0]);
    F3 b2 = f3sub(p[2], p[1]);
    F3 b3 = f3sub(p[3], p[2]);
    F3 n1 = f3cross(b1, b2);
    F3 n2 = f3cross(b2, b3);
    float L = sqrtf(f3dot(b2, b2));
    F3 u = f3scale(b2, 1.f / L);
    F3 m1 = f3cross(n1, u);
    float yv = f3dot(m1, n2);
    float xv = f3dot(n1, n2);
    float h = sqrtf(xv*xv + yv*yv);
    float cphi = xv / h;
    float sphi = yv / h;

    // reverse mode, dphi = 1
    float invd = 1.f / (h*h);
    float dX = -yv * invd;
    float dY =  xv * invd;
    F3 dn1 = f3scale(n2, dX);
    F3 dn2 = f3scale(n1, dX);
    F3 dm1 = f3scale(n2, dY);
    dn2 = f3add(dn2, f3scale(m1, dY));
    dn1 = f3add(dn1, f3cross(u, dm1));
    F3 du = f3cross(dm1, n1);
    float ud = f3dot(u, du);
    F3 db2 = f3scale(f3sub(du, f3scale(u, ud)), 1.f / L);
    db2 = f3add(db2, f3cross(b3, dn2));
    F3 db3 = f3cross(dn2, b2);
    F3 db1 = f3cross(b2, dn1);
    db2 = f3add(db2, f3cross(dn1, b1));

    F3 g0 = f3scale(db1, -1.f);
    F3 g1 = f3sub(db1, db2);
    F3 g2 = f3sub(db2, db3);
    F3 g3 = db3;

    ws[WS_XRAW + i]       = cphi;
    ws[WS_XRAW + NCV + i] = sphi;
    ws[WS_DCV + 0*NCV  + i] = g0.x; ws[WS_DCV + 1*NCV  + i] = g0.y; ws[WS_DCV + 2*NCV  + i] = g0.z;
    ws[WS_DCV + 3*NCV  + i] = g1.x; ws[WS_DCV + 4*NCV  + i] = g1.y; ws[WS_DCV + 5*NCV  + i] = g1.z;
    ws[WS_DCV + 6*NCV  + i] = g2.x; ws[WS_DCV + 7*NCV  + i] = g2.y; ws[WS_DCV + 8*NCV  + i] = g2.z;
    ws[WS_DCV + 9*NCV  + i] = g3.x; ws[WS_DCV + 10*NCV + i] = g3.y; ws[WS_DCV + 11*NCV + i] = g3.z;

    cx  = cphi + sphi;
    cx2 = cphi*cphi + sphi*sphi;
  }

  #pragma unroll
  for (int o = 1; o < 64; o <<= 1) { cx += __shfl_xor(cx, o); cx2 += __shfl_xor(cx2, o); }
  __shared__ float sa[4], sb[4];
  int w = tid >> 6, l = tid & 63;
  if (l == 0) { sa[w] = cx; sb[w] = cx2; }
  __syncthreads();
  if (tid == 0) {
    ws[WS_LNP + blockIdx.x]         = sa[0] + sa[1] + sa[2] + sa[3];
    ws[WS_LNP + NB_CV + blockIdx.x] = sb[0] + sb[1] + sb[2] + sb[3];
  }
}

// ---------------- K2: z0 partials (R2-proven body) + fused per-model MLP (ticket) ----------------
__global__ void k_z0(const float4* __restrict__ W0, const float* __restrict__ gamma,
                     const float* __restrict__ beta,
                     const float* __restrict__ b0,
                     const float* __restrict__ W1, const float* __restrict__ b1,
                     const float* __restrict__ W2, const float* __restrict__ b2,
                     const float* __restrict__ W3, const float* __restrict__ b3,
                     const float* __restrict__ W4, const float* __restrict__ b4,
                     float* __restrict__ ws) {
  __shared__ union {
    struct { float stats[2]; float yl[1024]; float red[4][16][4]; float lastflag; } z;
    struct { float Wl[3][64*65]; float hs[4][64]; float part[256]; float ds[64]; } mlp;
  } sm;
  int tid = threadIdx.x;
  int jb = blockIdx.x, m = blockIdx.y;
  int j0 = jb * 1024;
  int jcount = min(1024, NX - j0);

  compute_mu_inv(ws, sm.z.stats, tid);
  __syncthreads();
  float mu = sm.z.stats[0], inv = sm.z.stats[1];
  for (int jj = tid; jj < 1024; jj += 256) {
    int gj = j0 + jj;
    sm.z.yl[jj] = (gj < NX) ? ((ws[WS_XRAW + gj] - mu) * inv * gamma[gj] + beta[gj]) : 0.f;
  }
  __syncthreads();

  int k4 = tid & 15;     // float4 column of the 64-wide row
  int r  = tid >> 4;     // row phase 0..15
  const float4* Wm = W0 + (size_t)m * NX * 16;
  float4 acc = {0.f, 0.f, 0.f, 0.f};
  #pragma unroll 4
  for (int j = r; j < jcount; j += 16) {       // scalar wv: registers, no scratch
    float y = sm.z.yl[j];
    float4 wv = Wm[(size_t)(j0 + j) * 16 + k4];
    acc.x += y * wv.x; acc.y += y * wv.y; acc.z += y * wv.z; acc.w += y * wv.w;
  }
  #pragma unroll
  for (int o = 16; o <= 32; o <<= 1) {
    acc.x += __shfl_xor(acc.x, o); acc.y += __shfl_xor(acc.y, o);
    acc.z += __shfl_xor(acc.z, o); acc.w += __shfl_xor(acc.w, o);
  }
  int w = tid >> 6, l = tid & 63;
  if (l < 16) {
    sm.z.red[w][l][0] = acc.x; sm.z.red[w][l][1] = acc.y;
    sm.z.red[w][l][2] = acc.z; sm.z.red[w][l][3] = acc.w;
  }
  __syncthreads();
  if (tid < 64) {
    int kk4 = tid & 15, c = tid >> 4;
    float v = sm.z.red[0][kk4][c] + sm.z.red[1][kk4][c] +
              sm.z.red[2][kk4][c] + sm.z.red[3][kk4][c];
    ws[WS_Z0P + ((size_t)m * JB + jb) * 64 + kk4 * 4 + c] = v;
  }
  __syncthreads();

  // per-model ticket: last-arriving block of model m runs the MLP inline (no spinning)
  if (tid == 0) {
    __threadfence();                            // release our partial
    unsigned old = atomicAdd((unsigned*)ws + WS_ZTICK + m, 1u);
    sm.z.lastflag = (old == JB - 1) ? 1.f : 0.f;
  }
  __syncthreads();
  bool last = (sm.z.lastflag != 0.f);
  __syncthreads();                              // everyone past lastflag read before LDS reuse
  if (!last) return;
  __threadfence();                              // acquire all 59 blocks' partials

  // ---- MLP fwd+bwd for model m (R3-proven body; partials via agent-scope loads) ----
  {
    int k = tid & 63, q = tid >> 6;
    const float* Wsrc0 = W1 + m*4096;
    const float* Wsrc1 = W2 + m*4096;
    const float* Wsrc2 = W3 + m*4096;
    for (int e = tid; e < 4096; e += 256) {
      int t = e >> 6, kk = e & 63;
      sm.mlp.Wl[0][t*65 + kk] = Wsrc0[e];
      sm.mlp.Wl[1][t*65 + kk] = Wsrc1[e];
      sm.mlp.Wl[2][t*65 + kk] = Wsrc2[e];
    }
    float p0 = 0.f;
    for (int jb2 = q; jb2 < JB; jb2 += 4)
      p0 += __hip_atomic_load(ws + WS_Z0P + ((size_t)m * JB + jb2) * 64 + k,
                              __ATOMIC_RELAXED, __HIP_MEMORY_SCOPE_AGENT);
    sm.mlp.part[tid] = p0;
    __syncthreads();
    if (tid < 64) {
      float a0 = b0[m*64 + k] + sm.mlp.part[k] + sm.mlp.part[64+k] + sm.mlp.part[128+k] + sm.mlp.part[192+k];
      sm.mlp.hs[0][k] = fmaxf(a0, 0.f);
    }
    __syncthreads();
    #pragma unroll
    for (int ll = 0; ll < 3; ll++) {
      float pp = 0.f;
      #pragma unroll
      for (int t0 = 0; t0 < 16; t0++) {
        int t = q*16 + t0;
        pp += sm.mlp.hs[ll][t] * sm.mlp.Wl[ll][t*65 + k];
      }
      sm.mlp.part[tid] = pp;
      __syncthreads();
      if (tid < 64) {
        const float* bl = (ll==0) ? b1 : (ll==1) ? b2 : b3;
        float a = bl[m*64+k] + sm.mlp.part[k] + sm.mlp.part[64+k] + sm.mlp.part[128+k] + sm.mlp.part[192+k];
        sm.mlp.hs[ll+1][k] = fmaxf(a, 0.f);
      }
      __syncthreads();
    }
    if (tid < 64) {
      float w4k = W4[m*64 + k];
      float e = sm.mlp.hs[3][k] * w4k;
      #pragma unroll
      for (int o = 1; o < 64; o <<= 1) e += __shfl_xor(e, o);
      if (k == 0) ws[WS_E + m] = e + b4[m];
      sm.mlp.ds[k] = (sm.mlp.hs[3][k] > 0.f) ? w4k : 0.f;
    }
    __syncthreads();
    #pragma unroll
    for (int ll = 2; ll >= 0; ll--) {
      float pp = 0.f;
      int t = k;
      #pragma unroll
      for (int k0 = 0; k0 < 16; k0++) {
        int kk = q*16 + k0;
        pp += sm.mlp.Wl[ll][t*65 + kk] * sm.mlp.ds[kk];
      }
      sm.mlp.part[tid] = pp;
      __syncthreads();
      if (tid < 64) {
        float dh = sm.mlp.part[k] + sm.mlp.part[64+k] + sm.mlp.part[128+k] + sm.mlp.part[192+k];
        float dz = (sm.mlp.hs[ll][k] > 0.f) ? dh : 0.f;
        if (ll == 0) ws[WS_DZ0 + m*64 + k] = dz;
        else         sm.mlp.ds[k] = dz;
      }
      __syncthreads();
    }
  }
}

// ---------------- K3: g[m][j] = (W0[m][j][:].dz0[m])*gamma[j]; clamped 4-deep batches ----------------
__global__ void k_bwdx(const float4* __restrict__ W0, const float* __restrict__ gamma,
                       float* __restrict__ ws) {
  __shared__ float stats[2];
  __shared__ float dz[64];
  __shared__ float sa[4], sb[4];
  int tid = threadIdx.x;
  int m = blockIdx.y, blk = blockIdx.x;

  compute_mu_inv(ws, stats, tid);
  if (tid >= 64 && tid < 128) dz[tid - 64] = ws[WS_DZ0 + m*64 + (tid - 64)];
  __syncthreads();
  float mu = stats[0], inv = stats[1];

  int c = tid & 15;        // float4 column within row
  int g = tid >> 4;        // row group 0..15
  float4 d4 = ((const float4*)dz)[c];

  float sg = 0.f, sgx = 0.f;
  #pragma unroll
  for (int it = 0; it < 4; it++) {
    int jbase = blk * 256 + it * 64 + g;
    float4 wv[4];
    #pragma unroll
    for (int u = 0; u < 4; u++) {
      int j = jbase + u * 16;
      int jc = min(j, NX - 1);               // unconditional init -> stays in registers
      wv[u] = W0[((size_t)m * NX + jc) * 16 + c];
    }
    #pragma unroll
    for (int u = 0; u < 4; u++) {
      int j = jbase + u * 16;
      float dot = wv[u].x*d4.x + wv[u].y*d4.y + wv[u].z*d4.z + wv[u].w*d4.w;
      #pragma unroll
      for (int o = 1; o < 16; o <<= 1) dot += __shfl_xor(dot, o);
      if (c == 0 && j < NX) {
        float gg = dot * gamma[j];
        ws[WS_G + (size_t)m * NX + j] = gg;
        float xh = (ws[WS_XRAW + j] - mu) * inv;
        sg += gg; sgx += gg * xh;
      }
    }
  }
  #pragma unroll
  for (int o = 1; o < 64; o <<= 1) { sg += __shfl_xor(sg, o); sgx += __shfl_xor(sgx, o); }
  int w = tid >> 6, l = tid & 63;
  if (l == 0) { sa[w] = sg; sb[w] = sgx; }
  __syncthreads();
  if (tid == 0) {
    ws[WS_SGP  + m * NBX + blk] = sa[0] + sa[1] + sa[2] + sa[3];
    ws[WS_SGXP + m * NBX + blk] = sb[0] + sb[1] + sb[2] + sb[3];
  }
}

// ---------------- K4: mean force + variance + sigma + fused scatter ----------------
__global__ void k_mf(const int* __restrict__ idx, float* __restrict__ ws,
                     float* __restrict__ out) {
  __shared__ float stats[2];
  __shared__ float sSg[NM], sSgx[NM];
  __shared__ float sv[4];
  __shared__ float ssig;
  int tid = threadIdx.x;
  int w = tid >> 6, l = tid & 63;

  compute_mu_inv(ws, stats, tid);
  for (int m = w; m < NM; m += 4) {
    float a = 0.f, b = 0.f;
    #pragma unroll 2
    for (int bb = l; bb < NBX; bb += 64) { a += ws[WS_SGP + m*NBX + bb]; b += ws[WS_SGXP + m*NBX + bb]; }
    #pragma unroll
    for (int o = 1; o < 64; o <<= 1) { a += __shfl_xor(a, o); b += __shfl_xor(b, o); }
    if (l == 0) { sSg[m] = a * (1.f / NX); sSgx[m] = b * (1.f / NX); }
  }
  __syncthreads();
  float mu = stats[0], inv = stats[1];

  int i = blockIdx.x * 256 + tid;
  float v = 0.f, fm = 0.f;
  if (i < NCV) {
    float cph = ws[WS_XRAW + i], sph = ws[WS_XRAW + NCV + i];
    float xc = (cph - mu) * inv, xs = (sph - mu) * inv;
    float f[NM];
    #pragma unroll
    for (int m = 0; m < NM; m++) {
      float gc = ws[WS_G + (size_t)m * NX + i];
      float gs = ws[WS_G + (size_t)m * NX + NCV + i];
      float dxc = inv * (gc - sSg[m] - xc * sSgx[m]);
      float dxs = inv * (gs - sSg[m] - xs * sSgx[m]);
      float dE = dxc * (-sph) + dxs * cph;
      f[m] = -dE;
      fm += f[m];
    }
    fm *= (1.f / NM);
    float acc = 0.f;
    #pragma unroll
    for (int m = 0; m < NM; m++) { float d = f[m] - fm; acc += d * d; }
    v = acc * (1.f / (NM - 1));
  }
  #pragma unroll
  for (int o = 1; o < 64; o <<= 1) v += __shfl_xor(v, o);
  if (l == 0) sv[w] = v;
  __syncthreads();
  if (tid == 0) {
    atomicAdd(&ws[WS_VARSUM], sv[0] + sv[1] + sv[2] + sv[3]);
    __threadfence();
    unsigned int* tick = (unsigned int*)ws + WS_TICKET;
    unsigned int old = atomicAdd(tick, 1u);
    if (old == NB_MF - 1) {
      float tot = atomicAdd(&ws[WS_VARSUM], 0.0f);   // coherent read after all adds
      float md = sqrtf(tot * (1.f / NCV));
      float isw = (3.0f - md) / (3.0f - 2.0f);
      float fl = floorf(isw);
      float smooth = 0.5f * (1.f + cosf(3.14159265358979323846f * (1.f - isw)));
      float sigma = (fl > 0.f) ? 1.f : ((fl < 0.f) ? 0.f : smooth);
      float em = 0.f;
      #pragma unroll
      for (int m = 0; m < NM; m++) em += ws[WS_E + m];
      em *= (1.f / NM);
      out[0] = em * sigma;
      __hip_atomic_store(ws + WS_SIGMA, sigma, __ATOMIC_RELAXED, __HIP_MEMORY_SCOPE_AGENT);
      __hip_atomic_store((unsigned int*)ws + WS_FLAG, 1u, __ATOMIC_RELEASE, __HIP_MEMORY_SCOPE_AGENT);
    }
    while (__hip_atomic_load((unsigned int*)ws + WS_FLAG, __ATOMIC_ACQUIRE,
                             __HIP_MEMORY_SCOPE_AGENT) == 0u) {
      __builtin_amdgcn_s_sleep(8);
    }
    ssig = __hip_atomic_load(ws + WS_SIGMA, __ATOMIC_RELAXED, __HIP_MEMORY_SCOPE_AGENT);
  }
  __syncthreads();
  float sigma = ssig;

  if (i < NCV) {
    float d[12];
    #pragma unroll
    for (int r = 0; r < 12; r++) d[r] = ws[WS_DCV + r*NCV + i];   // coalesced
    int4 q4 = *(const int4*)(idx + i*4);
    float s = fm * sigma;
    float* fp = out + 1;
    atomicAdd(&fp[(size_t)q4.x*3 + 0], s*d[0]);
    atomicAdd(&fp[(size_t)q4.x*3 + 1], s*d[1]);
    atomicAdd(&fp[(size_t)q4.x*3 + 2], s*d[2]);
    atomicAdd(&fp[(size_t)q4.y*3 + 0], s*d[3]);
    atomicAdd(&fp[(size_t)q4.y*3 + 1], s*d[4]);
    atomicAdd(&fp[(size_t)q4.y*3 + 2], s*d[5]);
    atomicAdd(&fp[(size_t)q4.z*3 + 0], s*d[6]);
    atomicAdd(&fp[(size_t)q4.z*3 + 1], s*d[7]);
    atomicAdd(&fp[(size_t)q4.z*3 + 2], s*d[8]);
    atomicAdd(&fp[(size_t)q4.w*3 + 0], s*d[9]);
    atomicAdd(&fp[(size_t)q4.w*3 + 1], s*d[10]);
    atomicAdd(&fp[(size_t)q4.w*3 + 2], s*d[11]);
  }
}

extern "C" void kernel_launch(void* const* d_in, const int* in_sizes, int n_in,
                              void* d_out, int out_size, void* d_ws, size_t ws_size,
                              hipStream_t stream) {
  const float* pos   = (const float*)d_in[0];
  const float* box   = (const float*)d_in[1];
  const int*   idx   = (const int*)  d_in[2];
  const float* gamma = (const float*)d_in[3];
  const float* beta  = (const float*)d_in[4];
  const float* W0 = (const float*)d_in[5];
  const float* b0 = (const float*)d_in[6];
  const float* W1 = (const float*)d_in[7];
  const float* b1 = (const float*)d_in[8];
  const float* W2 = (const float*)d_in[9];
  const float* b2 = (const float*)d_in[10];
  const float* W3 = (const float*)d_in[11];
  const float* b3 = (const float*)d_in[12];
  const float* W4 = (const float*)d_in[13];
  const float* b4 = (const float*)d_in[14];
  float* ws  = (float*)d_ws;
  float* out = (float*)d_out;

  k_cv<<<NB_CV, 256, 0, stream>>>(pos, box, idx, ws, out);
  k_z0<<<dim3(JB, NM), 256, 0, stream>>>((const float4*)W0, gamma, beta,
                                         b0, W1, b1, W2, b2, W3, b3, W4, b4, ws);
  k_bwdx<<<dim3(NBX, NM), 256, 0, stream>>>((const float4*)W0, gamma, ws);
  k_mf<<<NB_MF, 256, 0, stream>>>(idx, ws, out);
}

// Round 9
// 104.460 us; speedup vs baseline: 1.1096x; 1.1096x over previous
//
#include <hip/hip_runtime.h>
#include <math.h>

#define NCV   30000
#define NX    60000
#define NM    8
#define LN_EPSF 1e-5f
#define NFORCE 9000000      // force floats (3M x 3); d_out = [energy, forces...]

#define NB_CV 512           // k_cv grid
#define JB    118           // z0 slabs of 512 rows (944 blocks = 3.7/CU)
#define SLAB  512
#define HALF  256
#define NBX   235           // bwdx 256-row blocks per model
#define NB_MF 118           // k_mf grid (<=256 => co-resident => spin-safe)

// ---------------- workspace layout (float offsets) ----------------
#define WS_XRAW   0          // 60000  (cos | sin)
#define WS_DCV    60000      // 360000 dphi/dx TRANSPOSED [12][30000]
#define WS_G      420000     // 480000 dE/dxhat*gamma per model (8 x 60000)
#define WS_LNP    900000     // 1024: [512 sum_x | 512 sum_x2]
#define WS_Z0P    901024     // 8*118*64 = 60416 z0 partials
#define WS_DZ0    961440     // 512
#define WS_E      961952     // 8
#define WS_SGP    961960     // 1880
#define WS_SGXP   963840     // 1880
#define WS_VARSUM 965720     // 1
#define WS_TICKET 965721     // 1 (uint bits)
#define WS_SIGMA  965722     // 1
#define WS_FLAG   965723     // 1 (uint bits)

struct F3 { float x, y, z; };
__device__ __forceinline__ F3 f3sub(F3 a, F3 b){ return {a.x-b.x, a.y-b.y, a.z-b.z}; }
__device__ __forceinline__ F3 f3add(F3 a, F3 b){ return {a.x+b.x, a.y+b.y, a.z+b.z}; }
__device__ __forceinline__ F3 f3scale(F3 a, float s){ return {a.x*s, a.y*s, a.z*s}; }
__device__ __forceinline__ float f3dot(F3 a, F3 b){ return a.x*b.x + a.y*b.y + a.z*b.z; }
__device__ __forceinline__ F3 f3cross(F3 a, F3 b){
  return { a.y*b.z - a.z*b.y, a.z*b.x - a.x*b.z, a.x*b.y - a.y*b.x };
}

// reduce LN per-block partials -> out2[0]=mu, out2[1]=inv_std  (wave 0 only; caller syncs)
__device__ __forceinline__ void compute_mu_inv(const float* __restrict__ ws, float* out2, int tid) {
  if (tid < 64) {
    float a = 0.f, b = 0.f;
    #pragma unroll 4
    for (int k = tid; k < NB_CV; k += 64) { a += ws[WS_LNP + k]; b += ws[WS_LNP + NB_CV + k]; }
    #pragma unroll
    for (int o = 1; o < 64; o <<= 1) { a += __shfl_xor(a, o); b += __shfl_xor(b, o); }
    if (tid == 0) {
      float mu  = a * (1.f / NX);
      float var = b * (1.f / NX) - mu * mu;
      out2[0] = mu;
      out2[1] = 1.f / sqrtf(var + LN_EPSF);
    }
  }
}

// ---------------- K1: dihedrals + grads + LN partials + zero forces ----------------
__global__ void k_cv(const float* __restrict__ pos, const float* __restrict__ box,
                     const int* __restrict__ idx, float* __restrict__ ws,
                     float* __restrict__ out) {
  int tid = threadIdx.x;
  int gtid = blockIdx.x * 256 + tid;

  // zero forces (grid-stride float4) — k_cv is latency-bound, write BW here is free (R2-verified)
  {
    float4 z4 = {0.f, 0.f, 0.f, 0.f};
    float4* fz = (float4*)(out + 4);
    const int NF4 = (NFORCE - 4) / 4;
    for (int i = gtid; i < NF4; i += NB_CV * 256) fz[i] = z4;
    if (gtid == 0) {
      out[1] = 0.f; out[2] = 0.f; out[3] = 0.f; out[NFORCE] = 0.f;
      ws[WS_VARSUM] = 0.f;
      ((unsigned int*)ws)[WS_TICKET] = 0u;
      ((unsigned int*)ws)[WS_FLAG]   = 0u;
    }
  }

  float cx = 0.f, cx2 = 0.f;
  int i = gtid;
  if (i < NCV) {
    float bx = box[0], by = box[4], bz = box[8];
    int4 q4 = *(const int4*)(idx + i*4);
    int pidx[4] = {q4.x, q4.y, q4.z, q4.w};
    F3 p[4];
    #pragma unroll
    for (int a = 0; a < 4; a++) {
      int pi = pidx[a];
      float X = pos[(size_t)pi*3 + 0];
      float Y = pos[(size_t)pi*3 + 1];
      float Z = pos[(size_t)pi*3 + 2];
      X -= floorf(X / bx) * bx;
      Y -= floorf(Y / by) * by;
      Z -= floorf(Z / bz) * bz;
      p[a] = {X, Y, Z};
    }
    F3 b1 = f3sub(p[1], p[0]);
    F3 b2 = f3sub(p[2], p[1]);
    F3 b3 = f3sub(p[3], p[2]);
    F3 n1 = f3cross(b1, b2);
    F3 n2 = f3cross(b2, b3);
    float L = sqrtf(f3dot(b2, b2));
    F3 u = f3scale(b2, 1.f / L);
    F3 m1 = f3cross(n1, u);
    float yv = f3dot(m1, n2);
    float xv = f3dot(n1, n2);
    float h = sqrtf(xv*xv + yv*yv);
    float cphi = xv / h;
    float sphi = yv / h;

    // reverse mode, dphi = 1
    float invd = 1.f / (h*h);
    float dX = -yv * invd;
    float dY =  xv * invd;
    F3 dn1 = f3scale(n2, dX);
    F3 dn2 = f3scale(n1, dX);
    F3 dm1 = f3scale(n2, dY);
    dn2 = f3add(dn2, f3scale(m1, dY));
    dn1 = f3add(dn1, f3cross(u, dm1));
    F3 du = f3cross(dm1, n1);
    float ud = f3dot(u, du);
    F3 db2 = f3scale(f3sub(du, f3scale(u, ud)), 1.f / L);
    db2 = f3add(db2, f3cross(b3, dn2));
    F3 db3 = f3cross(dn2, b2);
    F3 db1 = f3cross(b2, dn1);
    db2 = f3add(db2, f3cross(dn1, b1));

    F3 g0 = f3scale(db1, -1.f);
    F3 g1 = f3sub(db1, db2);
    F3 g2 = f3sub(db2, db3);
    F3 g3 = db3;

    ws[WS_XRAW + i]       = cphi;
    ws[WS_XRAW + NCV + i] = sphi;
    ws[WS_DCV + 0*NCV  + i] = g0.x; ws[WS_DCV + 1*NCV  + i] = g0.y; ws[WS_DCV + 2*NCV  + i] = g0.z;
    ws[WS_DCV + 3*NCV  + i] = g1.x; ws[WS_DCV + 4*NCV  + i] = g1.y; ws[WS_DCV + 5*NCV  + i] = g1.z;
    ws[WS_DCV + 6*NCV  + i] = g2.x; ws[WS_DCV + 7*NCV  + i] = g2.y; ws[WS_DCV + 8*NCV  + i] = g2.z;
    ws[WS_DCV + 9*NCV  + i] = g3.x; ws[WS_DCV + 10*NCV + i] = g3.y; ws[WS_DCV + 11*NCV + i] = g3.z;

    cx  = cphi + sphi;
    cx2 = cphi*cphi + sphi*sphi;
  }

  #pragma unroll
  for (int o = 1; o < 64; o <<= 1) { cx += __shfl_xor(cx, o); cx2 += __shfl_xor(cx2, o); }
  __shared__ float sa[4], sb[4];
  int w = tid >> 6, l = tid & 63;
  if (l == 0) { sa[w] = cx; sb[w] = cx2; }
  __syncthreads();
  if (tid == 0) {
    ws[WS_LNP + blockIdx.x]         = sa[0] + sa[1] + sa[2] + sa[3];
    ws[WS_LNP + NB_CV + blockIdx.x] = sb[0] + sb[1] + sb[2] + sb[3];
  }
}

// ---------------- K2: z0 partials; 512-row slabs, dual streams, 8 loads in flight ----------------
__global__ __launch_bounds__(256, 2)   // VGPR cap 128: room for 8 in-flight float4, 4 waves/SIMD
void k_z0(const float4* __restrict__ W0, const float* __restrict__ gamma,
          const float* __restrict__ beta, float* __restrict__ ws) {
  __shared__ float stats[2];
  __shared__ float yl[SLAB];
  __shared__ float red[4][16][4];
  int tid = threadIdx.x;
  int jb = blockIdx.x, m = blockIdx.y;
  int j0 = jb * SLAB;                  // last block (jb=117): rows 59904..60415 -> tail path

  compute_mu_inv(ws, stats, tid);
  __syncthreads();
  float mu = stats[0], inv = stats[1];
  #pragma unroll
  for (int jj = tid; jj < SLAB; jj += 256) {
    int gj = j0 + jj;
    yl[jj] = (gj < NX) ? ((ws[WS_XRAW + gj] - mu) * inv * gamma[gj] + beta[gj]) : 0.f;
  }
  __syncthreads();

  int k4 = tid & 15;     // float4 column of the 64-wide row
  int r  = tid >> 4;     // row phase 0..15
  const float4* Wm = W0 + (size_t)m * NX * 16;
  float4 acc0 = {0.f, 0.f, 0.f, 0.f};
  float4 acc1 = {0.f, 0.f, 0.f, 0.f};

  if (j0 + SLAB <= NX) {               // hot path: 936 of 944 blocks, no bounds checks
    #pragma unroll 4
    for (int j = r; j < HALF; j += 16) {
      float4 wv0 = Wm[(size_t)(j0 + j) * 16 + k4];
      float4 wv1 = Wm[(size_t)(j0 + HALF + j) * 16 + k4];
      float y0 = yl[j];
      float y1 = yl[HALF + j];
      acc0.x += y0 * wv0.x; acc0.y += y0 * wv0.y; acc0.z += y0 * wv0.z; acc0.w += y0 * wv0.w;
      acc1.x += y1 * wv1.x; acc1.y += y1 * wv1.y; acc1.z += y1 * wv1.z; acc1.w += y1 * wv1.w;
    }
  } else {                             // tail: clamped index, yl zero-pad gives 0 contribution
    #pragma unroll 4
    for (int j = r; j < HALF; j += 16) {
      int g0 = min(j0 + j, NX - 1);
      int g1 = min(j0 + HALF + j, NX - 1);
      float4 wv0 = Wm[(size_t)g0 * 16 + k4];
      float4 wv1 = Wm[(size_t)g1 * 16 + k4];
      float y0 = yl[j];
      float y1 = yl[HALF + j];
      acc0.x += y0 * wv0.x; acc0.y += y0 * wv0.y; acc0.z += y0 * wv0.z; acc0.w += y0 * wv0.w;
      acc1.x += y1 * wv1.x; acc1.y += y1 * wv1.y; acc1.z += y1 * wv1.z; acc1.w += y1 * wv1.w;
    }
  }
  float4 acc = {acc0.x + acc1.x, acc0.y + acc1.y, acc0.z + acc1.z, acc0.w + acc1.w};
  #pragma unroll
  for (int o = 16; o <= 32; o <<= 1) {
    acc.x += __shfl_xor(acc.x, o); acc.y += __shfl_xor(acc.y, o);
    acc.z += __shfl_xor(acc.z, o); acc.w += __shfl_xor(acc.w, o);
  }
  int w = tid >> 6, l = tid & 63;
  if (l < 16) {
    red[w][l][0] = acc.x; red[w][l][1] = acc.y; red[w][l][2] = acc.z; red[w][l][3] = acc.w;
  }
  __syncthreads();
  if (tid < 64) {
    int kk4 = tid & 15, c = tid >> 4;
    float v = red[0][kk4][c] + red[1][kk4][c] + red[2][kk4][c] + red[3][kk4][c];
    ws[WS_Z0P + ((size_t)m * JB + jb) * 64 + kk4 * 4 + c] = v;
  }
}

// ---------------- K3: tiny MLP fwd+bwd per model, LDS-staged weights ----------------
__global__ void k_mlp(const float* __restrict__ ws_ro, const float* __restrict__ b0,
                      const float* __restrict__ W1, const float* __restrict__ b1,
                      const float* __restrict__ W2, const float* __restrict__ b2,
                      const float* __restrict__ W3, const float* __restrict__ b3,
                      const float* __restrict__ W4, const float* __restrict__ b4,
                      float* __restrict__ ws) {
  int m = blockIdx.x;
  int tid = threadIdx.x;
  int k = tid & 63, q = tid >> 6;           // q = t-quarter 0..3
  __shared__ float Wl[3][64*65];            // 65-stride pad: conflict-free both directions
  __shared__ float hs[4][64];
  __shared__ float part[256];
  __shared__ float ds[64];

  const float* Wsrc0 = W1 + m*4096;
  const float* Wsrc1 = W2 + m*4096;
  const float* Wsrc2 = W3 + m*4096;
  for (int e = tid; e < 4096; e += 256) {
    int t = e >> 6, kk = e & 63;
    Wl[0][t*65 + kk] = Wsrc0[e];
    Wl[1][t*65 + kk] = Wsrc1[e];
    Wl[2][t*65 + kk] = Wsrc2[e];
  }

  float p0 = 0.f;
  for (int jb = q; jb < JB; jb += 4)
    p0 += ws_ro[WS_Z0P + ((size_t)m * JB + jb) * 64 + k];
  part[tid] = p0;
  __syncthreads();
  if (tid < 64) {
    float a0 = b0[m*64 + k] + part[k] + part[64+k] + part[128+k] + part[192+k];
    hs[0][k] = fmaxf(a0, 0.f);
  }
  __syncthreads();

  #pragma unroll
  for (int l = 0; l < 3; l++) {
    float pp = 0.f;
    #pragma unroll
    for (int t0 = 0; t0 < 16; t0++) {
      int t = q*16 + t0;
      pp += hs[l][t] * Wl[l][t*65 + k];
    }
    part[tid] = pp;
    __syncthreads();
    if (tid < 64) {
      const float* bl = (l==0) ? b1 : (l==1) ? b2 : b3;
      float a = bl[m*64+k] + part[k] + part[64+k] + part[128+k] + part[192+k];
      hs[l+1][k] = fmaxf(a, 0.f);
    }
    __syncthreads();
  }

  if (tid < 64) {
    float w4k = W4[m*64 + k];
    float e = hs[3][k] * w4k;
    #pragma unroll
    for (int o = 1; o < 64; o <<= 1) e += __shfl_xor(e, o);
    if (k == 0) ws[WS_E + m] = e + b4[m];
    ds[k] = (hs[3][k] > 0.f) ? w4k : 0.f;
  }
  __syncthreads();

  #pragma unroll
  for (int l = 2; l >= 0; l--) {
    float pp = 0.f;
    int t = k;
    #pragma unroll
    for (int k0 = 0; k0 < 16; k0++) {
      int kk = q*16 + k0;
      pp += Wl[l][t*65 + kk] * ds[kk];
    }
    part[tid] = pp;
    __syncthreads();
    if (tid < 64) {
      float dh = part[k] + part[64+k] + part[128+k] + part[192+k];
      float dz = (hs[l][k] > 0.f) ? dh : 0.f;
      if (l == 0) ws[WS_DZ0 + m*64 + k] = dz;
      else        ds[k] = dz;
    }
    __syncthreads();
  }
}

// ---------------- K4: g[m][j] = (W0[m][j][:].dz0[m])*gamma[j]; clamped 4-deep batches ----------------
__global__ void k_bwdx(const float4* __restrict__ W0, const float* __restrict__ gamma,
                       float* __restrict__ ws) {
  __shared__ float stats[2];
  __shared__ float dz[64];
  __shared__ float sa[4], sb[4];
  int tid = threadIdx.x;
  int m = blockIdx.y, blk = blockIdx.x;

  compute_mu_inv(ws, stats, tid);
  if (tid >= 64 && tid < 128) dz[tid - 64] = ws[WS_DZ0 + m*64 + (tid - 64)];
  __syncthreads();
  float mu = stats[0], inv = stats[1];

  int c = tid & 15;        // float4 column within row
  int g = tid >> 4;        // row group 0..15
  float4 d4 = ((const float4*)dz)[c];

  float sg = 0.f, sgx = 0.f;
  #pragma unroll
  for (int it = 0; it < 4; it++) {
    int jbase = blk * 256 + it * 64 + g;
    float4 wv[4];
    #pragma unroll
    for (int u = 0; u < 4; u++) {
      int j = jbase + u * 16;
      int jc = min(j, NX - 1);               // unconditional init -> stays in registers
      wv[u] = W0[((size_t)m * NX + jc) * 16 + c];
    }
    #pragma unroll
    for (int u = 0; u < 4; u++) {
      int j = jbase + u * 16;
      float dot = wv[u].x*d4.x + wv[u].y*d4.y + wv[u].z*d4.z + wv[u].w*d4.w;
      #pragma unroll
      for (int o = 1; o < 16; o <<= 1) dot += __shfl_xor(dot, o);
      if (c == 0 && j < NX) {
        float gg = dot * gamma[j];
        ws[WS_G + (size_t)m * NX + j] = gg;
        float xh = (ws[WS_XRAW + j] - mu) * inv;
        sg += gg; sgx += gg * xh;
      }
    }
  }
  #pragma unroll
  for (int o = 1; o < 64; o <<= 1) { sg += __shfl_xor(sg, o); sgx += __shfl_xor(sgx, o); }
  int w = tid >> 6, l = tid & 63;
  if (l == 0) { sa[w] = sg; sb[w] = sgx; }
  __syncthreads();
  if (tid == 0) {
    ws[WS_SGP  + m * NBX + blk] = sa[0] + sa[1] + sa[2] + sa[3];
    ws[WS_SGXP + m * NBX + blk] = sb[0] + sb[1] + sb[2] + sb[3];
  }
}

// ---------------- K5: mean force + variance + sigma + fused scatter ----------------
__global__ void k_mf(const int* __restrict__ idx, float* __restrict__ ws,
                     float* __restrict__ out) {
  __shared__ float stats[2];
  __shared__ float sSg[NM], sSgx[NM];
  __shared__ float sv[4];
  __shared__ float ssig;
  int tid = threadIdx.x;
  int w = tid >> 6, l = tid & 63;

  compute_mu_inv(ws, stats, tid);
  for (int m = w; m < NM; m += 4) {
    float a = 0.f, b = 0.f;
    #pragma unroll 2
    for (int bb = l; bb < NBX; bb += 64) { a += ws[WS_SGP + m*NBX + bb]; b += ws[WS_SGXP + m*NBX + bb]; }
    #pragma unroll
    for (int o = 1; o < 64; o <<= 1) { a += __shfl_xor(a, o); b += __shfl_xor(b, o); }
    if (l == 0) { sSg[m] = a * (1.f / NX); sSgx[m] = b * (1.f / NX); }
  }
  __syncthreads();
  float mu = stats[0], inv = stats[1];

  int i = blockIdx.x * 256 + tid;
  float v = 0.f, fm = 0.f;
  if (i < NCV) {
    float cph = ws[WS_XRAW + i], sph = ws[WS_XRAW + NCV + i];
    float xc = (cph - mu) * inv, xs = (sph - mu) * inv;
    float f[NM];
    #pragma unroll
    for (int m = 0; m < NM; m++) {
      float gc = ws[WS_G + (size_t)m * NX + i];
      float gs = ws[WS_G + (size_t)m * NX + NCV + i];
      float dxc = inv * (gc - sSg[m] - xc * sSgx[m]);
      float dxs = inv * (gs - sSg[m] - xs * sSgx[m]);
      float dE = dxc * (-sph) + dxs * cph;
      f[m] = -dE;
      fm += f[m];
    }
    fm *= (1.f / NM);
    float acc = 0.f;
    #pragma unroll
    for (int m = 0; m < NM; m++) { float d = f[m] - fm; acc += d * d; }
    v = acc * (1.f / (NM - 1));
  }
  #pragma unroll
  for (int o = 1; o < 64; o <<= 1) v += __shfl_xor(v, o);
  if (l == 0) sv[w] = v;
  __syncthreads();
  if (tid == 0) {
    atomicAdd(&ws[WS_VARSUM], sv[0] + sv[1] + sv[2] + sv[3]);
    __threadfence();
    unsigned int* tick = (unsigned int*)ws + WS_TICKET;
    unsigned int old = atomicAdd(tick, 1u);
    if (old == NB_MF - 1) {
      float tot = atomicAdd(&ws[WS_VARSUM], 0.0f);   // coherent read after all adds
      float md = sqrtf(tot * (1.f / NCV));
      float isw = (3.0f - md) / (3.0f - 2.0f);
      float fl = floorf(isw);
      float smooth = 0.5f * (1.f + cosf(3.14159265358979323846f * (1.f - isw)));
      float sigma = (fl > 0.f) ? 1.f : ((fl < 0.f) ? 0.f : smooth);
      float em = 0.f;
      #pragma unroll
      for (int m = 0; m < NM; m++) em += ws[WS_E + m];
      em *= (1.f / NM);
      out[0] = em * sigma;
      __hip_atomic_store(ws + WS_SIGMA, sigma, __ATOMIC_RELAXED, __HIP_MEMORY_SCOPE_AGENT);
      __hip_atomic_store((unsigned int*)ws + WS_FLAG, 1u, __ATOMIC_RELEASE, __HIP_MEMORY_SCOPE_AGENT);
    }
    while (__hip_atomic_load((unsigned int*)ws + WS_FLAG, __ATOMIC_ACQUIRE,
                             __HIP_MEMORY_SCOPE_AGENT) == 0u) {
      __builtin_amdgcn_s_sleep(8);
    }
    ssig = __hip_atomic_load(ws + WS_SIGMA, __ATOMIC_RELAXED, __HIP_MEMORY_SCOPE_AGENT);
  }
  __syncthreads();
  float sigma = ssig;

  if (i < NCV) {
    float d[12];
    #pragma unroll
    for (int r = 0; r < 12; r++) d[r] = ws[WS_DCV + r*NCV + i];   // coalesced
    int4 q4 = *(const int4*)(idx + i*4);
    float s = fm * sigma;
    float* fp = out + 1;
    atomicAdd(&fp[(size_t)q4.x*3 + 0], s*d[0]);
    atomicAdd(&fp[(size_t)q4.x*3 + 1], s*d[1]);
    atomicAdd(&fp[(size_t)q4.x*3 + 2], s*d[2]);
    atomicAdd(&fp[(size_t)q4.y*3 + 0], s*d[3]);
    atomicAdd(&fp[(size_t)q4.y*3 + 1], s*d[4]);
    atomicAdd(&fp[(size_t)q4.y*3 + 2], s*d[5]);
    atomicAdd(&fp[(size_t)q4.z*3 + 0], s*d[6]);
    atomicAdd(&fp[(size_t)q4.z*3 + 1], s*d[7]);
    atomicAdd(&fp[(size_t)q4.z*3 + 2], s*d[8]);
    atomicAdd(&fp[(size_t)q4.w*3 + 0], s*d[9]);
    atomicAdd(&fp[(size_t)q4.w*3 + 1], s*d[10]);
    atomicAdd(&fp[(size_t)q4.w*3 + 2], s*d[11]);
  }
}

extern "C" void kernel_launch(void* const* d_in, const int* in_sizes, int n_in,
                              void* d_out, int out_size, void* d_ws, size_t ws_size,
                              hipStream_t stream) {
  const float* pos   = (const float*)d_in[0];
  const float* box   = (const float*)d_in[1];
  const int*   idx   = (const int*)  d_in[2];
  const float* gamma = (const float*)d_in[3];
  const float* beta  = (const float*)d_in[4];
  const float* W0 = (const float*)d_in[5];
  const float* b0 = (const float*)d_in[6];
  const float* W1 = (const float*)d_in[7];
  const float* b1 = (const float*)d_in[8];
  const float* W2 = (const float*)d_in[9];
  const float* b2 = (const float*)d_in[10];
  const float* W3 = (const float*)d_in[11];
  const float* b3 = (const float*)d_in[12];
  const float* W4 = (const float*)d_in[13];
  const float* b4 = (const float*)d_in[14];
  float* ws  = (float*)d_ws;
  float* out = (float*)d_out;

  k_cv<<<NB_CV, 256, 0, stream>>>(pos, box, idx, ws, out);
  k_z0<<<dim3(JB, NM), 256, 0, stream>>>((const float4*)W0, gamma, beta, ws);
  k_mlp<<<NM, 256, 0, stream>>>(ws, b0, W1, b1, W2, b2, W3, b3, W4, b4, ws);
  k_bwdx<<<dim3(NBX, NM), 256, 0, stream>>>((const float4*)W0, gamma, ws);
  k_mf<<<NB_MF, 256, 0, stream>>>(idx, ws, out);
}

// Round 10
// 95.420 us; speedup vs baseline: 1.2147x; 1.0947x over previous
//
#include <hip/hip_runtime.h>
#include <math.h>

#define NCV   30000
#define NX    60000
#define NM    8
#define LN_EPSF 1e-5f
#define NFORCE 9000000      // force floats (3M x 3); d_out = [energy, forces...]

#define NB_CV 512           // k_cv grid
#define JB    59            // k_z0 j-blocks of 1024 (R2-proven)
#define NBX   235           // k_bwdx blocks per model (256 rows each)
#define NB_MF 118           // k_mf grid

// ---------------- workspace layout (float offsets) — exact R2 ----------------
#define WS_XRAW   0          // 60000  (cos | sin)
#define WS_DCV    60000      // 360000 dphi/dx (30000 x 12, row-major as in R2)
#define WS_G      420000     // 480000 dE/dxhat*gamma per model (8 x 60000)
#define WS_MF     900000     // 30000
#define WS_LNP    930000     // 1024: [512 sum_x | 512 sum_x2]
#define WS_Z0P    931024     // 8*59*64 z0 partials
#define WS_DZ0    961232     // 512
#define WS_E      961744     // 8
#define WS_SGP    961752     // 8*235
#define WS_SGXP   963632     // 1880
#define WS_VARSUM 965512     // 1
#define WS_TICKET 965513     // 1 (uint bits)
#define WS_SIGMA  965514     // 1

struct F3 { float x, y, z; };
__device__ __forceinline__ F3 f3sub(F3 a, F3 b){ return {a.x-b.x, a.y-b.y, a.z-b.z}; }
__device__ __forceinline__ F3 f3add(F3 a, F3 b){ return {a.x+b.x, a.y+b.y, a.z+b.z}; }
__device__ __forceinline__ F3 f3scale(F3 a, float s){ return {a.x*s, a.y*s, a.z*s}; }
__device__ __forceinline__ float f3dot(F3 a, F3 b){ return a.x*b.x + a.y*b.y + a.z*b.z; }
__device__ __forceinline__ F3 f3cross(F3 a, F3 b){
  return { a.y*b.z - a.z*b.y, a.z*b.x - a.x*b.z, a.x*b.y - a.y*b.x };
}

// reduce LN per-block partials -> out2[0]=mu, out2[1]=inv_std  (wave 0 only; caller syncs)
__device__ __forceinline__ void compute_mu_inv(const float* __restrict__ ws, float* out2, int tid) {
  if (tid < 64) {
    float a = 0.f, b = 0.f;
    #pragma unroll 4
    for (int k = tid; k < NB_CV; k += 64) { a += ws[WS_LNP + k]; b += ws[WS_LNP + NB_CV + k]; }
    #pragma unroll
    for (int o = 1; o < 64; o <<= 1) { a += __shfl_xor(a, o); b += __shfl_xor(b, o); }
    if (tid == 0) {
      float mu  = a * (1.f / NX);
      float var = b * (1.f / NX) - mu * mu;
      out2[0] = mu;
      out2[1] = 1.f / sqrtf(var + LN_EPSF);
    }
  }
}

// ---------------- K1: dihedrals + grads + LN partials + zero forces (R2) ----------------
__global__ void k_cv(const float* __restrict__ pos, const float* __restrict__ box,
                     const int* __restrict__ idx, float* __restrict__ ws,
                     float* __restrict__ out) {
  int tid = threadIdx.x;
  int gtid = blockIdx.x * 256 + tid;

  {
    float4 z4 = {0.f, 0.f, 0.f, 0.f};
    float4* fz = (float4*)(out + 4);
    const int NF4 = (NFORCE - 4) / 4;
    for (int i = gtid; i < NF4; i += NB_CV * 256) fz[i] = z4;
    if (gtid == 0) {
      out[1] = 0.f; out[2] = 0.f; out[3] = 0.f; out[NFORCE] = 0.f;
      ws[WS_VARSUM] = 0.f;
      ((unsigned int*)ws)[WS_TICKET] = 0u;
    }
  }

  float cx = 0.f, cx2 = 0.f;
  int i = gtid;
  if (i < NCV) {
    float bx = box[0], by = box[4], bz = box[8];
    int4 q4 = *(const int4*)(idx + i*4);
    int pidx[4] = {q4.x, q4.y, q4.z, q4.w};
    F3 p[4];
    #pragma unroll
    for (int a = 0; a < 4; a++) {
      int pi = pidx[a];
      float X = pos[(size_t)pi*3 + 0];
      float Y = pos[(size_t)pi*3 + 1];
      float Z = pos[(size_t)pi*3 + 2];
      X -= floorf(X / bx) * bx;
      Y -= floorf(Y / by) * by;
      Z -= floorf(Z / bz) * bz;
      p[a] = {X, Y, Z};
    }
    F3 b1 = f3sub(p[1], p[0]);
    F3 b2 = f3sub(p[2], p[1]);
    F3 b3 = f3sub(p[3], p[2]);
    F3 n1 = f3cross(b1, b2);
    F3 n2 = f3cross(b2, b3);
    float L = sqrtf(f3dot(b2, b2));
    F3 u = f3scale(b2, 1.f / L);
    F3 m1 = f3cross(n1, u);
    float yv = f3dot(m1, n2);
    float xv = f3dot(n1, n2);
    float h = sqrtf(xv*xv + yv*yv);
    float cphi = xv / h;
    float sphi = yv / h;

    float invd = 1.f / (h*h);
    float dX = -yv * invd;
    float dY =  xv * invd;
    F3 dn1 = f3scale(n2, dX);
    F3 dn2 = f3scale(n1, dX);
    F3 dm1 = f3scale(n2, dY);
    dn2 = f3add(dn2, f3scale(m1, dY));
    dn1 = f3add(dn1, f3cross(u, dm1));
    F3 du = f3cross(dm1, n1);
    float ud = f3dot(u, du);
    F3 db2 = f3scale(f3sub(du, f3scale(u, ud)), 1.f / L);
    db2 = f3add(db2, f3cross(b3, dn2));
    F3 db3 = f3cross(dn2, b2);
    F3 db1 = f3cross(b2, dn1);
    db2 = f3add(db2, f3cross(dn1, b1));

    F3 g0 = f3scale(db1, -1.f);
    F3 g1 = f3sub(db1, db2);
    F3 g2 = f3sub(db2, db3);
    F3 g3 = db3;

    ws[WS_XRAW + i]       = cphi;
    ws[WS_XRAW + NCV + i] = sphi;
    float* dc = ws + WS_DCV + (size_t)i * 12;
    dc[0] = g0.x; dc[1]  = g0.y; dc[2]  = g0.z;
    dc[3] = g1.x; dc[4]  = g1.y; dc[5]  = g1.z;
    dc[6] = g2.x; dc[7]  = g2.y; dc[8]  = g2.z;
    dc[9] = g3.x; dc[10] = g3.y; dc[11] = g3.z;

    cx  = cphi + sphi;
    cx2 = cphi*cphi + sphi*sphi;
  }

  #pragma unroll
  for (int o = 1; o < 64; o <<= 1) { cx += __shfl_xor(cx, o); cx2 += __shfl_xor(cx2, o); }
  __shared__ float sa[4], sb[4];
  int w = tid >> 6, l = tid & 63;
  if (l == 0) { sa[w] = cx; sb[w] = cx2; }
  __syncthreads();
  if (tid == 0) {
    ws[WS_LNP + blockIdx.x]         = sa[0] + sa[1] + sa[2] + sa[3];
    ws[WS_LNP + NB_CV + blockIdx.x] = sb[0] + sb[1] + sb[2] + sb[3];
  }
}

// ---------------- K2: z0 partials; R2 body at 512 threads (THE one change) ----------------
__global__ __launch_bounds__(512)
void k_z0(const float4* __restrict__ W0, const float* __restrict__ gamma,
          const float* __restrict__ beta, float* __restrict__ ws) {
  __shared__ float stats[2];
  __shared__ float yl[1024];
  __shared__ float red[8][16][4];
  int tid = threadIdx.x;
  int jb = blockIdx.x, m = blockIdx.y;
  int j0 = jb * 1024;
  int jcount = min(1024, NX - j0);

  compute_mu_inv(ws, stats, tid);
  __syncthreads();
  float mu = stats[0], inv = stats[1];
  for (int jj = tid; jj < 1024; jj += 512) {
    int gj = j0 + jj;
    yl[jj] = (gj < NX) ? ((ws[WS_XRAW + gj] - mu) * inv * gamma[gj] + beta[gj]) : 0.f;
  }
  __syncthreads();

  int k4 = tid & 15;     // float4 column of the 64-wide row
  int r  = tid >> 4;     // row phase 0..31
  const float4* Wm = W0 + (size_t)m * NX * 16;
  float4 acc = {0.f, 0.f, 0.f, 0.f};
  #pragma unroll 4
  for (int j = r; j < jcount; j += 32) {       // scalar wv: registers, no scratch
    float y = yl[j];
    float4 wv = Wm[(size_t)(j0 + j) * 16 + k4];
    acc.x += y * wv.x; acc.y += y * wv.y; acc.z += y * wv.z; acc.w += y * wv.w;
  }
  #pragma unroll
  for (int o = 16; o <= 32; o <<= 1) {          // fold 4 row-phases within each wave
    acc.x += __shfl_xor(acc.x, o); acc.y += __shfl_xor(acc.y, o);
    acc.z += __shfl_xor(acc.z, o); acc.w += __shfl_xor(acc.w, o);
  }
  int w = tid >> 6, l = tid & 63;
  if (l < 16) {
    red[w][l][0] = acc.x; red[w][l][1] = acc.y; red[w][l][2] = acc.z; red[w][l][3] = acc.w;
  }
  __syncthreads();
  if (tid < 64) {
    int kk4 = tid & 15, c = tid >> 4;
    float v = 0.f;
    #pragma unroll
    for (int ww = 0; ww < 8; ww++) v += red[ww][kk4][c];
    ws[WS_Z0P + ((size_t)m * JB + jb) * 64 + kk4 * 4 + c] = v;
  }
}

// ---------------- K3: tiny MLP fwd+bwd per model (R2 64-thread version) ----------------
__global__ void k_mlp(const float* __restrict__ ws_ro, const float* __restrict__ b0,
                      const float* __restrict__ W1, const float* __restrict__ b1,
                      const float* __restrict__ W2, const float* __restrict__ b2,
                      const float* __restrict__ W3, const float* __restrict__ b3,
                      const float* __restrict__ W4, const float* __restrict__ b4,
                      float* __restrict__ ws) {
  int m = blockIdx.x, k = threadIdx.x;   // 64 threads
  __shared__ float h0[64], h1[64], h2[64], d3[64], d2[64], d1[64];
  const float* W1m = W1 + m * 4096;
  const float* W2m = W2 + m * 4096;
  const float* W3m = W3 + m * 4096;

  float a0 = b0[m*64 + k];
  #pragma unroll 4
  for (int jb = 0; jb < JB; jb++) a0 += ws_ro[WS_Z0P + ((size_t)m * JB + jb) * 64 + k];
  h0[k] = fmaxf(a0, 0.f);
  __syncthreads();
  float a1 = b1[m*64 + k];
  #pragma unroll 8
  for (int t = 0; t < 64; t++) a1 += h0[t] * W1m[t*64 + k];
  h1[k] = fmaxf(a1, 0.f);
  __syncthreads();
  float a2 = b2[m*64 + k];
  #pragma unroll 8
  for (int t = 0; t < 64; t++) a2 += h1[t] * W2m[t*64 + k];
  h2[k] = fmaxf(a2, 0.f);
  __syncthreads();
  float a3 = b3[m*64 + k];
  #pragma unroll 8
  for (int t = 0; t < 64; t++) a3 += h2[t] * W3m[t*64 + k];
  float h3 = fmaxf(a3, 0.f);

  float w4 = W4[m*64 + k];
  float e = h3 * w4;
  #pragma unroll
  for (int o = 1; o < 64; o <<= 1) e += __shfl_xor(e, o);
  if (k == 0) ws[WS_E + m] = e + b4[m];

  float dz3 = (a3 > 0.f) ? w4 : 0.f;
  d3[k] = dz3;
  __syncthreads();
  float dh2 = 0.f;
  #pragma unroll 8
  for (int t = 0; t < 64; t++) dh2 += W3m[k*64 + t] * d3[t];
  float dz2 = (a2 > 0.f) ? dh2 : 0.f;
  d2[k] = dz2;
  __syncthreads();
  float dh1 = 0.f;
  #pragma unroll 8
  for (int t = 0; t < 64; t++) dh1 += W2m[k*64 + t] * d2[t];
  float dz1 = (a1 > 0.f) ? dh1 : 0.f;
  d1[k] = dz1;
  __syncthreads();
  float dh0 = 0.f;
  #pragma unroll 8
  for (int t = 0; t < 64; t++) dh0 += W1m[k*64 + t] * d1[t];
  ws[WS_DZ0 + m*64 + k] = (a0 > 0.f) ? dh0 : 0.f;
}

// ---------------- K4: g = (W0 . dz0)*gamma; LN-bwd partials (R2 version) ----------------
__global__ void k_bwdx(const float4* __restrict__ W0, const float* __restrict__ gamma,
                       float* __restrict__ ws) {
  __shared__ float stats[2];
  __shared__ float dz[64];
  __shared__ float sa[4], sb[4];
  int tid = threadIdx.x;
  int m = blockIdx.y, blk = blockIdx.x;

  compute_mu_inv(ws, stats, tid);
  if (tid >= 64 && tid < 128) dz[tid - 64] = ws[WS_DZ0 + m*64 + (tid - 64)];
  __syncthreads();
  float mu = stats[0], inv = stats[1];

  int c = tid & 15;
  int g = tid >> 4;
  const float4* dz4 = (const float4*)dz;
  float4 d4 = dz4[c];

  float sg = 0.f, sgx = 0.f;
  #pragma unroll 2
  for (int it = 0; it < 16; it++) {
    int j = blk * 256 + it * 16 + g;
    if (j < NX) {
      float4 wv = W0[((size_t)m * NX + j) * 16 + c];
      float dot = wv.x*d4.x + wv.y*d4.y + wv.z*d4.z + wv.w*d4.w;
      #pragma unroll
      for (int o = 1; o < 16; o <<= 1) dot += __shfl_xor(dot, o);
      if (c == 0) {
        float gg = dot * gamma[j];
        ws[WS_G + (size_t)m * NX + j] = gg;
        float xh = (ws[WS_XRAW + j] - mu) * inv;
        sg += gg; sgx += gg * xh;
      }
    }
  }
  #pragma unroll
  for (int o = 1; o < 64; o <<= 1) { sg += __shfl_xor(sg, o); sgx += __shfl_xor(sgx, o); }
  int w = tid >> 6, l = tid & 63;
  if (l == 0) { sa[w] = sg; sb[w] = sgx; }
  __syncthreads();
  if (tid == 0) {
    ws[WS_SGP  + m * NBX + blk] = sa[0] + sa[1] + sa[2] + sa[3];
    ws[WS_SGXP + m * NBX + blk] = sb[0] + sb[1] + sb[2] + sb[3];
  }
}

// ---------------- K5: mean force + variance; last block does sigma + energy (R2) ----------------
__global__ void k_mf(float* __restrict__ ws, float* __restrict__ out) {
  __shared__ float stats[2];
  __shared__ float sSg[NM], sSgx[NM];
  __shared__ float sv[4];
  int tid = threadIdx.x;
  int w = tid >> 6, l = tid & 63;

  compute_mu_inv(ws, stats, tid);
  for (int m = w; m < NM; m += 4) {
    float a = 0.f, b = 0.f;
    #pragma unroll 2
    for (int bb = l; bb < NBX; bb += 64) { a += ws[WS_SGP + m*NBX + bb]; b += ws[WS_SGXP + m*NBX + bb]; }
    #pragma unroll
    for (int o = 1; o < 64; o <<= 1) { a += __shfl_xor(a, o); b += __shfl_xor(b, o); }
    if (l == 0) { sSg[m] = a * (1.f / NX); sSgx[m] = b * (1.f / NX); }
  }
  __syncthreads();
  float mu = stats[0], inv = stats[1];

  int i = blockIdx.x * 256 + tid;
  float v = 0.f;
  if (i < NCV) {
    float cph = ws[WS_XRAW + i], sph = ws[WS_XRAW + NCV + i];
    float xc = (cph - mu) * inv, xs = (sph - mu) * inv;
    float f[NM];
    float fm = 0.f;
    #pragma unroll
    for (int m = 0; m < NM; m++) {
      float gc = ws[WS_G + (size_t)m * NX + i];
      float gs = ws[WS_G + (size_t)m * NX + NCV + i];
      float dxc = inv * (gc - sSg[m] - xc * sSgx[m]);
      float dxs = inv * (gs - sSg[m] - xs * sSgx[m]);
      float dE = dxc * (-sph) + dxs * cph;
      f[m] = -dE;
      fm += f[m];
    }
    fm *= (1.f / NM);
    ws[WS_MF + i] = fm;
    float acc = 0.f;
    #pragma unroll
    for (int m = 0; m < NM; m++) { float d = f[m] - fm; acc += d * d; }
    v = acc * (1.f / (NM - 1));
  }
  #pragma unroll
  for (int o = 1; o < 64; o <<= 1) v += __shfl_xor(v, o);
  if (l == 0) sv[w] = v;
  __syncthreads();
  if (tid == 0) {
    atomicAdd(&ws[WS_VARSUM], sv[0] + sv[1] + sv[2] + sv[3]);
    __threadfence();
    unsigned int* tick = (unsigned int*)ws + WS_TICKET;
    unsigned int old = atomicAdd(tick, 1u);
    if (old == NB_MF - 1) {
      float tot = atomicAdd(&ws[WS_VARSUM], 0.0f);
      float md = sqrtf(tot * (1.f / NCV));
      float isw = (3.0f - md) / (3.0f - 2.0f);
      float fl = floorf(isw);
      float smooth = 0.5f * (1.f + cosf(3.14159265358979323846f * (1.f - isw)));
      float sigma = (fl > 0.f) ? 1.f : ((fl < 0.f) ? 0.f : smooth);
      float em = 0.f;
      #pragma unroll
      for (int m = 0; m < NM; m++) em += ws[WS_E + m];
      em *= (1.f / NM);
      out[0] = em * sigma;
      ws[WS_SIGMA] = sigma;          // visible to k_scatter at kernel boundary
    }
  }
}

// ---------------- K6: scatter forces (R2 version) ----------------
__global__ void k_scatter(const int* __restrict__ idx, const float* __restrict__ ws,
                          float* __restrict__ forces) {
  int t = blockIdx.x * blockDim.x + threadIdx.x;
  if (t >= NCV * 12) return;
  int i = t / 12, r = t - i * 12;
  int a = r / 3, d = r - a * 3;
  float sigma = ws[WS_SIGMA];
  float contrib = ws[WS_MF + i] * ws[WS_DCV + (size_t)i * 12 + r] * sigma;
  atomicAdd(&forces[(size_t)idx[i*4 + a] * 3 + d], contrib);
}

extern "C" void kernel_launch(void* const* d_in, const int* in_sizes, int n_in,
                              void* d_out, int out_size, void* d_ws, size_t ws_size,
                              hipStream_t stream) {
  const float* pos   = (const float*)d_in[0];
  const float* box   = (const float*)d_in[1];
  const int*   idx   = (const int*)  d_in[2];
  const float* gamma = (const float*)d_in[3];
  const float* beta  = (const float*)d_in[4];
  const float* W0 = (const float*)d_in[5];
  const float* b0 = (const float*)d_in[6];
  const float* W1 = (const float*)d_in[7];
  const float* b1 = (const float*)d_in[8];
  const float* W2 = (const float*)d_in[9];
  const float* b2 = (const float*)d_in[10];
  const float* W3 = (const float*)d_in[11];
  const float* b3 = (const float*)d_in[12];
  const float* W4 = (const float*)d_in[13];
  const float* b4 = (const float*)d_in[14];
  float* ws  = (float*)d_ws;
  float* out = (float*)d_out;

  k_cv<<<NB_CV, 256, 0, stream>>>(pos, box, idx, ws, out);
  k_z0<<<dim3(JB, NM), 512, 0, stream>>>((const float4*)W0, gamma, beta, ws);
  k_mlp<<<NM, 64, 0, stream>>>(ws, b0, W1, b1, W2, b2, W3, b3, W4, b4, ws);
  k_bwdx<<<dim3(NBX, NM), 256, 0, stream>>>((const float4*)W0, gamma, ws);
  k_mf<<<NB_MF, 256, 0, stream>>>(ws, out);
  k_scatter<<<(NCV * 12 + 255) / 256, 256, 0, stream>>>(idx, ws, out + 1);
}